// Round 11
// baseline (74.894 us; speedup 1.0000x reference)
//
#include <hip/hip_runtime.h>
#include <float.h>

// ChamferLoss via MFMA, verts-as-rows, Q=4 point-tiles/wave.
// B=4, N=16384, M=4096, fp32 in/out.
// loss[b] = (1/N) * sum_n min_m max(||p_bn - v_bm||^2, 0)
//
// d2 = pp + (v2 - 2 p.v). Bracket on the MATRIX pipe via split-bf16 in K=16
// of mfma_f32_32x32x16_bf16 (encoding + layouts validated R6-R10, absmax 0):
//   A row (VERT):   [-2vh x3, -2vh x3, -2vl x3, v2h, v2l, 0...]
//   B col (POINT):  [ph x3, pl x3, ph x3, 1, 1, 0...]
// A lane's 16 C-regs = 16 verts of ONE point (col = lane&31) -> min folds
// across regs via v_min3_f32; lane L / L+32 merge via one shfl_xor(32).
//
// R11: (1) Q=4 point-tiles per wave -> one vert ds_read_b128 feeds 4
// independent MFMAs (LDS-read instrs /4; MFMA pipe ~8.3K cyc/CU is now the
// binding constraint). (2) No pre-pass: verts staged+transformed in-block
// (R9-validated write_vert, same byte layout). (3) NCHUNK=16 -> 8 KB LDS,
// 2048 blocks = 8 blocks/CU = 32 waves/CU for MFMA latency hiding.

typedef __bf16 bf16x8 __attribute__((ext_vector_type(8)));
typedef float  f32x16 __attribute__((ext_vector_type(16)));

constexpr int B = 4, N = 16384, M = 4096;
constexpr int BN = B * N;
constexpr int NCHUNK = 16;
constexpr int CHUNK_V = M / NCHUNK;      // 256 verts per chunk
constexpr int TILES = CHUNK_V / 32;      // 8 vert tiles per chunk
constexpr int TPB = 256;                 // 4 waves
constexpr int Q = 4;                     // point tiles per wave
constexpr int PPW = 32 * Q;              // 128 points per wave
constexpr int PPB = 4 * PPW;             // 512 points per block
constexpr int PBLK = BN / PPB;           // 128 point-blocks (32 per batch)
// grid = PBLK * NCHUNK = 2048 blocks

// Vert u -> LDS frag slot (R9/R10-validated layout):
//   base = (u>>5)*1024 + (u&31)*16 ; K0-7 at +0, K8-15 at +512
__device__ __forceinline__ void write_vert(char* bp, int u,
                                           float x, float y, float z) {
    __bf16 xh = (__bf16)x, yh = (__bf16)y, zh = (__bf16)z;
    float xhf = (float)xh, yhf = (float)yh, zhf = (float)zh;
    __bf16 xl = (__bf16)(x - xhf), yl = (__bf16)(y - yhf), zl = (__bf16)(z - zhf);
    float v2 = fmaf(x, x, fmaf(y, y, z * z));
    __bf16 v2h = (__bf16)v2;
    __bf16 v2l = (__bf16)(v2 - (float)v2h);
    __bf16 zero = (__bf16)0.0f;
    bf16x8 h0, h1;
    h0[0] = (__bf16)(-2.0f * xhf); h0[1] = (__bf16)(-2.0f * yhf);
    h0[2] = (__bf16)(-2.0f * zhf);
    h0[3] = h0[0]; h0[4] = h0[1]; h0[5] = h0[2];
    h0[6] = (__bf16)(-2.0f * (float)xl); h0[7] = (__bf16)(-2.0f * (float)yl);
    h1[0] = (__bf16)(-2.0f * (float)zl); h1[1] = v2h; h1[2] = v2l;
    h1[3] = zero; h1[4] = zero; h1[5] = zero; h1[6] = zero; h1[7] = zero;
    char* base = bp + ((u >> 5) << 10) + ((u & 31) << 4);
    *(bf16x8*)base         = h0;
    *(bf16x8*)(base + 512) = h1;
}

// ---- Main: 2048 blocks = 128 point-blocks x 16 chunks, 8 blocks/CU. ----
// Wave w: 128 points (4 col-tiles) vs the block's 256-vert chunk (8 tiles).
// partial[chunk][point] = pp + min over chunk verts of (v2 - 2 p.v).
__global__ __launch_bounds__(TPB) void chamfer_mfma(
    const float* __restrict__ src, const float* __restrict__ tv,
    float* __restrict__ partial, float* __restrict__ out)
{
    __shared__ char lds[TILES * 1024];           // 8 KB vert A-frags
    const int blk   = blockIdx.x;
    const int chunk = blk & 15;
    const int pblk  = blk >> 4;                  // 0..127
    const int b     = pblk >> 5;                 // 32 point-blocks per batch
    const int t     = threadIdx.x;
    const int w     = t >> 6, L = t & 63;
    const int half  = L >> 5, c = L & 31;

    // Zero output (poisoned each launch); main completes before reduce.
    if (blk == 0 && t < B) out[t] = 0.0f;

    // Stage this chunk's 256 verts: thread t transforms vert t in-register
    // and writes its 32 B frag (2 x ds_write_b128).
    {
        const float* vs = tv + ((size_t)b * M + (size_t)chunk * CHUNK_V) * 3 + 3 * t;
        write_vert(lds, t, vs[0], vs[1], vs[2]);
    }

    // B-frags for this wave's Q point tiles (col = c), kept in registers.
    const int pbase = pblk * PPB + w * PPW;
    __bf16 one = (__bf16)1.0f, zero = (__bf16)0.0f;
    bf16x8 bP[Q];
    float pp[Q];
#pragma unroll
    for (int q = 0; q < Q; ++q) {
        const int gp = pbase + q * 32 + c;
        float x = src[3 * gp], y = src[3 * gp + 1], z = src[3 * gp + 2];
        pp[q] = fmaf(x, x, fmaf(y, y, z * z));
        __bf16 xh = (__bf16)x, yh = (__bf16)y, zh = (__bf16)z;
        __bf16 xl = (__bf16)(x - (float)xh), yl = (__bf16)(y - (float)yh),
               zl = (__bf16)(z - (float)zh);
        bf16x8 f;
        if (half == 0) { f[0]=xh; f[1]=yh; f[2]=zh; f[3]=xl; f[4]=yl; f[5]=zl; f[6]=xh; f[7]=yh; }
        else { f[0]=zh; f[1]=one; f[2]=one; f[3]=zero; f[4]=zero; f[5]=zero; f[6]=zero; f[7]=zero; }
        bP[q] = f;
    }

    float mn[Q][8];
#pragma unroll
    for (int q = 0; q < Q; ++q)
#pragma unroll
        for (int u = 0; u < 8; ++u) mn[q][u] = FLT_MAX;
    f32x16 zeroC;
#pragma unroll
    for (int r = 0; r < 16; ++r) zeroC[r] = 0.0f;

    __syncthreads();

    // Inner loop: 1 ds_read_b128 -> 4 independent MFMAs -> 32 v_min3_f32.
    const int laneoff = half * 512 + c * 16;
#pragma unroll 2
    for (int tl = 0; tl < TILES; ++tl) {
        bf16x8 av = *(const bf16x8*)(lds + tl * 1024 + laneoff);
#pragma unroll
        for (int q = 0; q < Q; ++q) {
            f32x16 C = __builtin_amdgcn_mfma_f32_32x32x16_bf16(av, bP[q], zeroC, 0, 0, 0);
#pragma unroll
            for (int u = 0; u < 8; ++u)
                mn[q][u] = fminf(fminf(mn[q][u], C[2 * u]), C[2 * u + 1]);
        }
    }

    // Epilogue: fold 8 accumulators, merge lane halves (L vs L+32 hold the
    // same point col), add pp, store 128 consecutive floats per wave.
    float m[Q];
#pragma unroll
    for (int q = 0; q < Q; ++q) {
        float a = fminf(fminf(mn[q][0], mn[q][1]), fminf(mn[q][2], mn[q][3]));
        float d = fminf(fminf(mn[q][4], mn[q][5]), fminf(mn[q][6], mn[q][7]));
        float x = fminf(a, d);
        m[q] = fminf(x, __shfl_xor(x, 32, 64)) + pp[q];
    }
    float* pout = partial + (size_t)chunk * BN + pbase;
    if (L < 32) {
        pout[c]      = m[0];
        pout[32 + c] = m[1];
    } else {
        pout[64 + c] = m[2];
        pout[96 + c] = m[3];
    }
}

// ---- Reduce: min over 16 chunks, clamp, per-batch mean. ----
__global__ __launch_bounds__(256) void chamfer_reduce(
    const float* __restrict__ partial, float* __restrict__ out)
{
    const int p = blockIdx.x * 256 + threadIdx.x;
    const int b = blockIdx.x >> 6;               // 64 blocks per batch
    float m = FLT_MAX;
#pragma unroll
    for (int cgr = 0; cgr < NCHUNK; ++cgr)
        m = fminf(m, partial[(size_t)cgr * BN + p]);
    float sum = fmaxf(m, 0.0f);

    for (int off = 32; off > 0; off >>= 1)
        sum += __shfl_down(sum, off, 64);
    __shared__ float acc[4];
    if ((threadIdx.x & 63) == 0) acc[threadIdx.x >> 6] = sum;
    __syncthreads();
    if (threadIdx.x == 0) {
        float s = acc[0] + acc[1] + acc[2] + acc[3];
        atomicAdd(&out[b], s * (1.0f / N));
    }
}

extern "C" void kernel_launch(void* const* d_in, const int* in_sizes, int n_in,
                              void* d_out, int out_size, void* d_ws, size_t ws_size,
                              hipStream_t stream) {
    const float* src = (const float*)d_in[0];    // (B, N, 3) fp32
    const float* tv  = (const float*)d_in[1];    // (B, M, 3) fp32
    float* out = (float*)d_out;                  // (B,) fp32
    float* partial = (float*)d_ws;               // NCHUNK*BN floats = 4 MB

    chamfer_mfma  <<<PBLK * NCHUNK, TPB, 0, stream>>>(src, tv, partial, out);
    chamfer_reduce<<<BN / 256, 256, 0, stream>>>(partial, out);
}